// Round 3
// baseline (160.253 us; speedup 1.0000x reference)
//
#include <hip/hip_runtime.h>

#define NN 768
#define FD 256
#define HD 128

// dinv[i] = rsqrt(1 + sum_j adj[i,j])   (self-loop adds 1 to row sum)
__global__ void k_dinv(const float* __restrict__ adj, float* __restrict__ dinv) {
    int i = blockIdx.x;
    int lane = threadIdx.x;  // 64 threads = 1 wave
    float s = 0.f;
    for (int j = lane; j < NN; j += 64) s += adj[i * NN + j];
#pragma unroll
    for (int off = 32; off > 0; off >>= 1) s += __shfl_down(s, off, 64);
    if (lane == 0) dinv[i] = rsqrtf(s + 1.0f);
}

// c[k] = sum_m time_emb[t,m] * we1[2H+m, k] + be1[k]
__global__ void k_c(const float* __restrict__ temb, const float* __restrict__ we1,
                    const float* __restrict__ be1, const int* __restrict__ tptr,
                    float* __restrict__ c) {
    __shared__ float ts[HD];
    int k = threadIdx.x;  // 128 threads
    int t = tptr[0];
    ts[k] = temb[t * HD + k];
    __syncthreads();
    float acc = be1[k];
    for (int m = 0; m < HD; ++m) acc += ts[m] * we1[(2 * HD + m) * HD + k];
    c[k] = acc;
}

// t1[i,k] = sum_m x[i,m] * w1[m,k]   (768x256 @ 256x128)
__global__ void k_xw1(const float* __restrict__ x, const float* __restrict__ w1,
                      float* __restrict__ t1) {
    __shared__ float xs[FD];
    int i = blockIdx.x, k = threadIdx.x;  // 128 threads
    for (int m = k; m < FD; m += HD) xs[m] = x[i * FD + m];
    __syncthreads();
    float acc = 0.f;
    for (int m = 0; m < FD; ++m) acc += xs[m] * w1[m * HD + k];
    t1[i * HD + k] = acc;
}

// hout[i,k] = relu( dinv[i] * sum_j (adj[i,j] + (i==j)) * dinv[j] * tin[j,k] )
__global__ void k_gcn(const float* __restrict__ adj, const float* __restrict__ dinv,
                      const float* __restrict__ tin, float* __restrict__ hout) {
    __shared__ float wrow[NN];
    int i = blockIdx.x, k = threadIdx.x;  // 128 threads
    for (int j = k; j < NN; j += HD)
        wrow[j] = (adj[i * NN + j] + (j == i ? 1.f : 0.f)) * dinv[j];
    __syncthreads();
    float acc = 0.f;
    for (int j = 0; j < NN; ++j) acc += wrow[j] * tin[j * HD + k];
    float v = dinv[i] * acc;
    hout[i * HD + k] = v > 0.f ? v : 0.f;
}

// Generic 128-wide row-linear: o[i,k] = (c?c[k]:0) + sum_m in[i,m] * w[m*HD+k]
// Stages the input row in LDS first, so o may alias in (in-place safe per row).
__global__ void k_lin(const float* __restrict__ in, const float* __restrict__ w,
                      const float* __restrict__ cvec, float* __restrict__ o) {
    __shared__ float ls[HD];
    int i = blockIdx.x, k = threadIdx.x;  // 128 threads
    ls[k] = in[i * HD + k];
    __syncthreads();
    float acc = cvec ? cvec[k] : 0.f;
    for (int m = 0; m < HD; ++m) acc += ls[m] * w[m * HD + k];
    o[i * HD + k] = acc;
}

// For 16x16 tile pair (bi<=bj): Lij = relu(p_i + q_j)@we2 + be2 ; Lji likewise;
// out[i,j] = out[j,i] = (sigmoid(Lij)+sigmoid(Lji))/2
__global__ void k_pair(const float* __restrict__ p, const float* __restrict__ q,
                       const float* __restrict__ we2, const float* __restrict__ be2,
                       float* __restrict__ out) {
    int bi = blockIdx.x, bj = blockIdx.y;
    if (bi > bj) return;
    __shared__ float pi[16][HD + 1], pj[16][HD + 1], qi[16][HD + 1], qj[16][HD + 1];
    __shared__ float w2s[HD];
    int tid = threadIdx.x;  // 256
    int i0 = bi * 16, j0 = bj * 16;
    for (int idx = tid; idx < 16 * HD; idx += 256) {
        int r = idx >> 7, cc = idx & 127;
        pi[r][cc] = p[(i0 + r) * HD + cc];
        qi[r][cc] = q[(i0 + r) * HD + cc];
        pj[r][cc] = p[(j0 + r) * HD + cc];
        qj[r][cc] = q[(j0 + r) * HD + cc];
    }
    if (tid < HD) w2s[tid] = we2[tid];
    __syncthreads();
    float bias = be2[0];
    int ti = tid & 15, tj = tid >> 4;
    float lij = bias, lji = bias;
    for (int k = 0; k < HD; ++k) {
        float w = w2s[k];
        float a = pi[ti][k] + qj[tj][k];
        lij += (a > 0.f ? a : 0.f) * w;
        float b = pj[tj][k] + qi[ti][k];
        lji += (b > 0.f ? b : 0.f) * w;
    }
    float sij = 1.f / (1.f + __expf(-lij));
    float sji = 1.f / (1.f + __expf(-lji));
    float v = 0.5f * (sij + sji);
    int i = i0 + ti, j = j0 + tj;
    out[i * NN + j] = v;
    out[j * NN + i] = v;
}

extern "C" void kernel_launch(void* const* d_in, const int* in_sizes, int n_in,
                              void* d_out, int out_size, void* d_ws, size_t ws_size,
                              hipStream_t stream) {
    const float* x    = (const float*)d_in[0];
    const float* adj  = (const float*)d_in[1];
    const float* w1   = (const float*)d_in[2];
    const float* w2   = (const float*)d_in[3];
    const float* temb = (const float*)d_in[4];
    const float* we1  = (const float*)d_in[5];
    const float* be1  = (const float*)d_in[6];
    const float* we2  = (const float*)d_in[7];
    const float* be2  = (const float*)d_in[8];
    const int* tptr   = (const int*)d_in[9];
    float* out        = (float*)d_out;

    // ws layout (f32): [0,768) dinv | [768,896) c | [1024, +98304) A | next 98304 B
    // total = (1024 + 2*98304)*4 = 790,528 bytes
    float* ws   = (float*)d_ws;
    float* dinv = ws;
    float* c    = ws + 768;
    float* A    = ws + 1024;
    float* B    = A + NN * HD;

    k_dinv<<<NN, 64, 0, stream>>>(adj, dinv);
    k_c   <<<1, HD, 0, stream>>>(temb, we1, be1, tptr, c);
    k_xw1 <<<NN, HD, 0, stream>>>(x, w1, A);                  // A = x @ w1
    k_gcn <<<NN, HD, 0, stream>>>(adj, dinv, A, B);           // B = relu(anorm @ A)
    k_lin <<<NN, HD, 0, stream>>>(B, w2, nullptr, A);         // A = B @ w2
    k_gcn <<<NN, HD, 0, stream>>>(adj, dinv, A, B);           // B = h2 = relu(anorm @ A)
    k_lin <<<NN, HD, 0, stream>>>(B, we1, c, A);              // A = p = h2 @ we1[:H] + c
    k_lin <<<NN, HD, 0, stream>>>(B, we1 + HD * HD, nullptr, B); // B = q = h2 @ we1[H:2H] (in place)
    dim3 grid(NN / 16, NN / 16);
    k_pair<<<grid, 256, 0, stream>>>(A, B, we2, be2, out);
}